// Round 9
// baseline (48.903 us; speedup 1.0000x reference)
//
#include <hip/hip_runtime.h>
#include <math.h>

#define BB 4
#define LL 256
#define TT 256
#define DD 512

// e^{2x} = exp2(x * 2/ln2)
#define EXP2K 2.885390081777927f

using short8 = __attribute__((ext_vector_type(8))) short;
using f32x4  = __attribute__((ext_vector_type(4))) float;

__device__ __forceinline__ unsigned cvt2bf(float a, float b) {
  unsigned r;
  asm("v_cvt_pk_bf16_f32 %0, %1, %2" : "=v"(r) : "v"(a), "v"(b));
  return r;  // lo = bf16(a), hi = bf16(b)
}

// ---------------------------------------------------------------------------
// Kernel 1: combined projection GEMM via bf16 MFMA, fp32 accumulate.
// Rows 0..1023:   E1 = exp(2*(x@W1^T+b1))   row-major [B*L, D]
// Rows 1024..2047: E2t = exp(2*(mem@W2^T+b2)) t-tiled layout:
//   E2t[b][tc][d>>2][t&63][d&3]  (score's j-walk is a contiguous 1KB-stride
//   stream inside a 128KB panel instead of 16KB jumps)
// ---------------------------------------------------------------------------
__global__ __launch_bounds__(256) void proj_gemm(
    const float* __restrict__ x, const float* __restrict__ mem,
    const float* __restrict__ W1, const float* __restrict__ b1,
    const float* __restrict__ W2, const float* __restrict__ b2,
    float* __restrict__ E1, float* __restrict__ E2t)
{
  __shared__ __align__(16) char Abuf[32 * 144];   // 32 rows x 64 bf16 (+pad)
  __shared__ __align__(16) char Bbuf[64 * 144];   // 64 cols x 64 bf16 (+pad)

  const int tid = threadIdx.x;
  const int m0 = blockIdx.x * 32;      // 0..2047 in steps of 32
  const int n0 = blockIdx.y * 64;      // 0..511  in steps of 64
  const bool second = (m0 >= BB * LL);

  const float* A    = second ? mem + (size_t)(m0 - BB * LL) * DD
                             : x   + (size_t)m0 * DD;
  const float* W    = second ? W2 : W1;
  const float* bias = second ? b2 : b1;

  const int srow = tid >> 4;           // 0..15 staging row
  const int kq   = (tid & 15) * 4;     // k quad within 64

  const int lane = tid & 63;
  const int wid  = tid >> 6;
  const int r0   = (wid & 1) * 16;     // wave row strip
  const int n0w  = (wid >> 1) * 32;    // wave col strip
  const int lr   = lane & 15;
  const int lg   = lane >> 4;

  const int aoff = (r0 + lr) * 144 + lg * 16;
  const int boff0 = (n0w + lr) * 144 + lg * 16;
  const int boff1 = (n0w + 16 + lr) * 144 + lg * 16;

  f32x4 acc0 = {0.f, 0.f, 0.f, 0.f};
  f32x4 acc1 = {0.f, 0.f, 0.f, 0.f};

  for (int kc = 0; kc < DD; kc += 64) {
    __syncthreads();   // previous iteration's frag reads done
#pragma unroll
    for (int p = 0; p < 2; ++p) {      // A: 32 rows
      const int r = srow + p * 16;
      float4 v = *(const float4*)(A + (size_t)r * DD + kc + kq);
      uint2 u = {cvt2bf(v.x, v.y), cvt2bf(v.z, v.w)};
      *(uint2*)(Abuf + r * 144 + kq * 2) = u;
    }
#pragma unroll
    for (int p = 0; p < 4; ++p) {      // B: 64 rows (= n cols)
      const int r = srow + p * 16;
      float4 v = *(const float4*)(W + (size_t)(n0 + r) * DD + kc + kq);
      uint2 u = {cvt2bf(v.x, v.y), cvt2bf(v.z, v.w)};
      *(uint2*)(Bbuf + r * 144 + kq * 2) = u;
    }
    __syncthreads();
#pragma unroll
    for (int ks = 0; ks < 2; ++ks) {
      short8 af  = *(const short8*)(Abuf + aoff  + ks * 64);
      short8 bf0 = *(const short8*)(Bbuf + boff0 + ks * 64);
      short8 bf1 = *(const short8*)(Bbuf + boff1 + ks * 64);
      acc0 = __builtin_amdgcn_mfma_f32_16x16x32_bf16(af, bf0, acc0, 0, 0, 0);
      acc1 = __builtin_amdgcn_mfma_f32_16x16x32_bf16(af, bf1, acc1, 0, 0, 0);
    }
  }

  // epilogue: C layout col=lane&15, row=(lane>>4)*4+i
#pragma unroll
  for (int nf = 0; nf < 2; ++nf) {
    const f32x4 a = nf ? acc1 : acc0;
    const int col = n0 + n0w + nf * 16 + lr;
    const float bv = bias[col];
#pragma unroll
    for (int i = 0; i < 4; ++i) {
      const int mrow = m0 + r0 + lg * 4 + i;   // global combined row
      const float val = exp2f((a[i] + bv) * EXP2K);
      if (!second) {
        E1[(size_t)mrow * DD + col] = val;
      } else {
        const int m2 = mrow - BB * LL;
        const int bb2 = m2 >> 8;               // batch
        const int t   = m2 & 255;
        E2t[(((size_t)(bb2 * 4 + (t >> 6)) * 128 + (col >> 2)) * 64
             + (t & 63)) * 4 + (col & 3)] = val;
      }
    }
  }
}

// ---------------------------------------------------------------------------
// Kernel 2: scores via exp-product trick, R=4 row sharing.
//   tanh(q+v) = 1 - 2/(Eq*Ev+1);  S = const - 2*sum_d w_d/(Eq*Ev+1)
// (const drops out of softmax -> store sum w*r only).
// One BLOCK per (b, row-QUAD lq, 64-t-tile tc); 4 waves = d-quarters
// (dq wave-uniform -> q/w scalar loads). Each vv vector load (16B) feeds
// 4 rows: 16 rcp + 32 fma. E2t walk is 1KB-stride streaming.
// Exact balanced map: g = lq>>4, tiles tc in [g,4): counts {64,48,32,16},
// 160 tasks/b -> 640 blocks (2.5/CU). Cross-dq reduce via 4KB LDS.
// ---------------------------------------------------------------------------
#define SROW(r, q)                                                            \
  a##r##0 = fmaf(w.x, __builtin_amdgcn_rcpf(fmaf(q.x, vv.x, 1.0f)), a##r##0); \
  a##r##1 = fmaf(w.y, __builtin_amdgcn_rcpf(fmaf(q.y, vv.y, 1.0f)), a##r##1); \
  a##r##2 = fmaf(w.z, __builtin_amdgcn_rcpf(fmaf(q.z, vv.z, 1.0f)), a##r##2); \
  a##r##3 = fmaf(w.w, __builtin_amdgcn_rcpf(fmaf(q.w, vv.w, 1.0f)), a##r##3)

__global__ __launch_bounds__(256) void score_kernel(
    const float* __restrict__ E1, const float* __restrict__ E2t,
    const float* __restrict__ wt, float* __restrict__ Sg)
{
  __shared__ float prt[4][4][64];      // (dq, row, t-lane)

  const int tid = threadIdx.x;
  const int tl  = tid & 63;
  const int dq  = __builtin_amdgcn_readfirstlane(tid >> 6);  // wave-uniform

  const int bid = blockIdx.x;          // 0..639
  const int b = bid / 160;
  const int u = bid - b * 160;
  int g, base;
  if (u < 112) { if (u < 64)  { g = 0; base = 0; }   else { g = 1; base = 64; } }
  else         { if (u < 144) { g = 2; base = 112; } else { g = 3; base = 144; } }
  const int v   = u - base;
  const int wdt = 4 - g;
  const int lq  = g * 16 + v / wdt;    // row quad: rows 4lq..4lq+3
  const int tc  = g + v % wdt;
  const int l0  = lq * 4;

  const float4* vp = (const float4*)E2t
      + ((size_t)(b * 4 + tc) * 128 + dq * 32) * 64 + tl;
  const float4* qp = (const float4*)(E1 + (size_t)(b * LL + l0) * DD) + dq * 32;
  const float4* wp = (const float4*)wt + dq * 32;

  float a00=0,a01=0,a02=0,a03=0, a10=0,a11=0,a12=0,a13=0;
  float a20=0,a21=0,a22=0,a23=0, a30=0,a31=0,a32=0,a33=0;
#pragma unroll 4
  for (int j = 0; j < 32; ++j) {
    const float4 vv = vp[(size_t)j * 64];
    const float4 w  = wp[j];
    const float4 q0 = qp[j];
    const float4 q1 = qp[j + 128];
    const float4 q2 = qp[j + 256];
    const float4 q3 = qp[j + 384];
    SROW(0, q0);
    SROW(1, q1);
    SROW(2, q2);
    SROW(3, q3);
  }
  prt[dq][0][tl] = (a00 + a01) + (a02 + a03);
  prt[dq][1][tl] = (a10 + a11) + (a12 + a13);
  prt[dq][2][tl] = (a20 + a21) + (a22 + a23);
  prt[dq][3][tl] = (a30 + a31) + (a32 + a33);
  __syncthreads();

  const int rr = tid >> 6;
  const int tt = tid & 63;
  const float* pp = &prt[0][rr][0];
  const float s = (pp[tt] + pp[256 + tt]) + (pp[512 + tt] + pp[768 + tt]);
  Sg[((size_t)(b * LL + l0 + rr)) * TT + tc * 64 + tt] = s;
}

// ---------------------------------------------------------------------------
// Kernel 3: softmax + PV. Block = (b, 4 rows, d-half) -> 512 blocks, 128 thr.
// Each of the 2 waves does 2 softmax rows serially; PV covers 256 d columns,
// mem rows read once per 4 l-rows. Triangle + memory mask applied here
// (unwritten Sg tiles are select-discarded before any arithmetic).
// ---------------------------------------------------------------------------
__global__ __launch_bounds__(128) void softmax_pv(
    const float* __restrict__ Sg, const float* __restrict__ mem,
    const int* __restrict__ mask, float* __restrict__ out)
{
  const int l0 = blockIdx.x * 4;
  const int b  = blockIdx.y;
  const int half = blockIdx.z;
  const int tid  = threadIdx.x;          // 0..127
  const int lane = tid & 63;
  const int wv   = tid >> 6;             // 0..1

  __shared__ __align__(16) float P[TT][4];
  __shared__ float rinvS[4];

  for (int rr = wv; rr < 4; rr += 2) {
    const int l = l0 + rr;
    const float* srow = Sg + ((size_t)(b * LL + l)) * TT;
    const int tb = lane * 4;
    float4 h = *(const float4*)(srow + tb);
    const int4 mk = *(const int4*)(mask + b * TT + tb);
    float v0 = (tb + 0 >= l && mk.x != 0) ? -2.0f * h.x : -1e30f;
    float v1 = (tb + 1 >= l && mk.y != 0) ? -2.0f * h.y : -1e30f;
    float v2 = (tb + 2 >= l && mk.z != 0) ? -2.0f * h.z : -1e30f;
    float v3 = (tb + 3 >= l && mk.w != 0) ? -2.0f * h.w : -1e30f;
    float mx = fmaxf(fmaxf(v0, v1), fmaxf(v2, v3));
#pragma unroll
    for (int o = 1; o < 64; o <<= 1) mx = fmaxf(mx, __shfl_xor(mx, o));
    float e0 = __expf(v0 - mx), e1 = __expf(v1 - mx),
          e2 = __expf(v2 - mx), e3 = __expf(v3 - mx);
    P[tb + 0][rr] = e0; P[tb + 1][rr] = e1;
    P[tb + 2][rr] = e2; P[tb + 3][rr] = e3;
    float sm = (e0 + e1) + (e2 + e3);
#pragma unroll
    for (int o = 1; o < 64; o <<= 1) sm += __shfl_xor(sm, o);
    if (lane == 0) rinvS[rr] = 1.0f / sm;
  }
  __syncthreads();

  const int dd = half * 256 + tid * 2;
  const float* mp = mem + ((size_t)b * TT) * DD + dd;
  float ax0=0,ay0=0, ax1=0,ay1=0, ax2=0,ay2=0, ax3=0,ay3=0;
#pragma unroll 2
  for (int t = l0; t < TT; ++t) {
    float4 p  = *(const float4*)(&P[t][0]);      // broadcast read
    float2 mv = *(const float2*)(mp + (size_t)t * DD);
    ax0 = fmaf(p.x, mv.x, ax0); ay0 = fmaf(p.x, mv.y, ay0);
    ax1 = fmaf(p.y, mv.x, ax1); ay1 = fmaf(p.y, mv.y, ay1);
    ax2 = fmaf(p.z, mv.x, ax2); ay2 = fmaf(p.z, mv.y, ay2);
    ax3 = fmaf(p.w, mv.x, ax3); ay3 = fmaf(p.w, mv.y, ay3);
  }
  const float r0 = rinvS[0], r1 = rinvS[1], r2 = rinvS[2], r3 = rinvS[3];
  float* op = out + ((size_t)(b * LL + l0)) * DD + dd;
  float2 o0 = {ax0 * r0, ay0 * r0}; *(float2*)(op)        = o0;
  float2 o1 = {ax1 * r1, ay1 * r1}; *(float2*)(op + DD)   = o1;
  float2 o2 = {ax2 * r2, ay2 * r2}; *(float2*)(op + 2*DD) = o2;
  float2 o3 = {ax3 * r3, ay3 * r3}; *(float2*)(op + 3*DD) = o3;
}

extern "C" void kernel_launch(void* const* d_in, const int* in_sizes, int n_in,
                              void* d_out, int out_size, void* d_ws, size_t ws_size,
                              hipStream_t stream) {
  const float* x   = (const float*)d_in[0];
  const float* mem = (const float*)d_in[1];
  const float* W1  = (const float*)d_in[2];
  const float* b1  = (const float*)d_in[3];
  const float* W2  = (const float*)d_in[4];
  const float* b2  = (const float*)d_in[5];
  const float* wt  = (const float*)d_in[6];
  const int* mask  = (const int*)d_in[8];
  float* outp = (float*)d_out;

  float* E1  = (float*)d_ws;                     // [B*L, D]             2 MB
  float* E2t = E1 + (size_t)BB * LL * DD;        // [B][4][128][64][4]   2 MB
  float* Sg  = E2t + (size_t)BB * TT * DD;       // [B][L][T]            1 MB  (5 MB)

  proj_gemm<<<dim3((BB * LL + BB * TT) / 32, DD / 64), 256, 0, stream>>>(
      x, mem, W1, b1, W2, b2, E1, E2t);
  score_kernel<<<640, 256, 0, stream>>>(E1, E2t, wt, Sg);
  softmax_pv<<<dim3(LL / 4, BB, 2), 128, 0, stream>>>(Sg, mem, mask, outp);
}